// Round 23
// baseline (1351.615 us; speedup 1.0000x reference)
//
#include <hip/hip_runtime.h>
#include <stdint.h>

// Problem constants
#define NB    32      // batch
#define NS    64      // src seq
#define TDEC  63      // decode steps (T-1)
#define NE    512     // embed dim
#define NH    1024    // hidden
#define NV    32000   // vocab

typedef float  floatx4 __attribute__((ext_vector_type(4)));
typedef short  short8  __attribute__((ext_vector_type(8)));
typedef short  short4v __attribute__((ext_vector_type(4)));

__device__ __forceinline__ float bf2f(short s) {
  return __uint_as_float(((uint32_t)(uint16_t)s) << 16);
}
__device__ __forceinline__ short f2bf(float f) {
  uint32_t u = __float_as_uint(f);
  uint32_t r = (u + 0x7fffu + ((u >> 16) & 1u)) >> 16;  // RNE
  return (short)(uint16_t)r;
}
__device__ __forceinline__ float sigm(float x) { return 1.f / (1.f + expf(-x)); }

// XCD-aware bijective block swizzle (valid when nwg % 8 == 0).
__device__ __forceinline__ int xcd_swz(int orig, int nwg) {
  return (orig & 7) * (nwg >> 3) + (orig >> 3);
}

// ---------------------------------------------------------------------------
// Transpose helpers (device): W[K][N] f32 tile(32x32 at bx,by) -> Wt[r(n)][K]
// perm: r = (n&1023)*4 + (n>>10)
// ---------------------------------------------------------------------------
__device__ __forceinline__ void tr_plain(
    const float* __restrict__ W, short* __restrict__ Wt, int K, int N,
    int bx, int by, int perm, float (*tile)[33], int tid)
{
  int k0 = bx * 32, n0 = by * 32;
  int tx = tid & 31, ty = tid >> 5;
#pragma unroll
  for (int r = 0; r < 32; r += 8)
    tile[ty + r][tx] = W[(size_t)(k0 + ty + r) * N + n0 + tx];
  __syncthreads();
  int kq = tid & 7, nl = tid >> 3;
  int n = n0 + nl;
  int rr = perm ? ((n & 1023) * 4 + (n >> 10)) : n;
  short4v v;
#pragma unroll
  for (int q = 0; q < 4; ++q) v[q] = f2bf(tile[kq * 4 + q][nl]);
  *(short4v*)&Wt[(size_t)rr * K + k0 + kq * 4] = v;
}

__device__ __forceinline__ void tr_split(
    const float* __restrict__ W, short* __restrict__ Wt_hi, short* __restrict__ Wt_lo,
    int K, int N, int bx, int by, int perm, float (*tile)[33], int tid)
{
  int k0 = bx * 32, n0 = by * 32;
  int tx = tid & 31, ty = tid >> 5;
#pragma unroll
  for (int r = 0; r < 32; r += 8)
    tile[ty + r][tx] = W[(size_t)(k0 + ty + r) * N + n0 + tx];
  __syncthreads();
  int kq = tid & 7, nl = tid >> 3;
  int n = n0 + nl;
  int rr = perm ? ((n & 1023) * 4 + (n >> 10)) : n;
  short4v vh, vl;
#pragma unroll
  for (int q = 0; q < 4; ++q) {
    float v = tile[kq * 4 + q][nl];
    short h = f2bf(v);
    vh[q] = h;
    vl[q] = f2bf(v - bf2f(h));
  }
  size_t o = (size_t)rr * K + k0 + kq * 4;
  *(short4v*)&Wt_hi[o] = vh;
  *(short4v*)&Wt_lo[o] = vl;
}

// ---------------------------------------------------------------------------
// prep_all: prework needed BEFORE the fused pre-GEMM: Wattn split, Wih perm,
// Whh split perm, gathers + src hi/lo split. 10240 blocks.
// ---------------------------------------------------------------------------
__global__ __launch_bounds__(256) void prep_all(
    const float* __restrict__ Wattn, const float* __restrict__ Wih,
    const float* __restrict__ Whh,
    const int* __restrict__ target,  const float* __restrict__ emb,
    const float* __restrict__ h0,    const float* __restrict__ c0,
    const float* __restrict__ brnn,  const float* __restrict__ src,
    short* __restrict__ WattnTh, short* __restrict__ WattnTl,
    short* __restrict__ WihTp,
    short* __restrict__ WhpHi,   short* __restrict__ WhpLo,
    short* __restrict__ xs, float* __restrict__ hf_all,
    short* __restrict__ hhi_all, short* __restrict__ hlo_all,
    float* __restrict__ c_buf, float* __restrict__ brnn_p,
    short* __restrict__ sAh, short* __restrict__ sAl)
{
  __shared__ float tile[32][33];
  const int blk = blockIdx.x;
  const int tid = threadIdx.x;

  if (blk < 2048) {
    tr_split(Wattn, WattnTh, WattnTl, 2048, 1024, blk & 63, blk >> 6, 0, tile, tid);
  } else if (blk < 4096) {
    int b = blk - 2048;
    tr_plain(Wih, WihTp, 512, 4096, b & 15, b >> 4, 1, tile, tid);
  } else if (blk < 8192) {
    int b = blk - 4096;
    tr_split(Whh, WhpHi, WhpLo, 1024, 4096, b & 31, b >> 5, 1, tile, tid);
  } else {
    const int NXS = TDEC * NB * NE;            // 1032192
    const int HN = NH * NB;                    // 32768
    const int NSRC = 2048 * 2048;              // 4194304
    int total = NXS + 2 * HN + 4096 + NSRC;
    int b = blk - 8192;                        // 0..2047
    for (int idx = b * 256 + tid; idx < total; idx += 2048 * 256) {
      if (idx < NXS) {
        int row = idx >> 9, e = idx & 511;     // row = t*32+b
        int t = row >> 5, bb = row & 31;
        int token = target[bb * 64 + t];
        xs[idx] = f2bf(emb[(size_t)token * NE + e]);
      } else if (idx < NXS + HN) {
        int r = idx - NXS;
        float v = h0[r];                       // [b][k], slot 0
        hf_all[r] = v;
        short hh = f2bf(v);
        hhi_all[r] = hh;
        hlo_all[r] = f2bf(v - bf2f(hh));
      } else if (idx < NXS + 2 * HN) {
        int r = idx - NXS - HN;
        c_buf[r] = c0[r];
      } else if (idx < NXS + 2 * HN + 4096) {
        int c = idx - NXS - 2 * HN;
        brnn_p[c] = brnn[(c & 3) * 1024 + (c >> 2)];
      } else {
        int e = idx - NXS - 2 * HN - 4096;
        float v = src[e];
        short h = f2bf(v);
        sAh[e] = h;
        sAl[e] = f2bf(v - bf2f(h));
      }
    }
  }
}

// ---------------------------------------------------------------------------
// bf16 MFMA GEMM: C[M][N] = A[M][K] * Bt[N][K]^T + bias.
// BK=64 K-loop (32 MFMA per barrier pair, pad-72 LDS, K % 64 == 0).
// SWZ=1: XCD-aware tile swizzle. f32-out epilogue cst overlays As/Bs.
// Output stores NONTEMPORAL (write-once streams).
// ---------------------------------------------------------------------------
template<int OUT_BF, int SWZ>
__global__ __launch_bounds__(256) void gemm_kernel(
    const short* __restrict__ Ab, const short* __restrict__ Bt,
    void* __restrict__ Cptr, const float* __restrict__ bias,
    int M, int N, int K)
{
  __shared__ char smem[2 * 128 * 72 * 2];   // 36864B: As | Bs; epilogue cst overlay
  short* As = (short*)smem;                 // [128*72]
  short* Bs = (short*)(smem + 128 * 72 * 2);
  float* cst = (float*)smem;                // f32-out epilogue staging (16896B)
  int tile_id = blockIdx.y * gridDim.x + blockIdx.x;
  if (SWZ) tile_id = xcd_swz(tile_id, gridDim.x * gridDim.y);
  const int m0 = (tile_id % gridDim.x) * 128;
  const int n0 = (tile_id / gridDim.x) * 128;
  const int tid = threadIdx.x;
  const int lane = tid & 63;
  const int wid = tid >> 6;
  const int wr = wid >> 1, wc = wid & 1;

  floatx4 acc[4][4] = {};
  const int row = tid >> 1;          // 0..127
  const int ks  = (tid & 1) << 5;    // 0 or 32

  for (int k0 = 0; k0 < K; k0 += 64) {
    {
      int gm = m0 + row;
      short8 v0, v1, v2, v3;
      if (gm < M) {
        const short* src = Ab + (size_t)gm * K + k0 + ks;
        v0 = *(const short8*)src;
        v1 = *(const short8*)(src + 8);
        v2 = *(const short8*)(src + 16);
        v3 = *(const short8*)(src + 24);
      } else {
#pragma unroll
        for (int c = 0; c < 8; ++c) { v0[c] = 0; v1[c] = 0; v2[c] = 0; v3[c] = 0; }
      }
      *(short8*)&As[row * 72 + ks]      = v0;
      *(short8*)&As[row * 72 + ks + 8]  = v1;
      *(short8*)&As[row * 72 + ks + 16] = v2;
      *(short8*)&As[row * 72 + ks + 24] = v3;
    }
    {
      const short* src = Bt + (size_t)(n0 + row) * K + k0 + ks;
      *(short8*)&Bs[row * 72 + ks]      = *(const short8*)src;
      *(short8*)&Bs[row * 72 + ks + 8]  = *(const short8*)(src + 8);
      *(short8*)&Bs[row * 72 + ks + 16] = *(const short8*)(src + 16);
      *(short8*)&Bs[row * 72 + ks + 24] = *(const short8*)(src + 24);
    }
    __syncthreads();

    const int kA = (lane >> 4) << 3;   // 0,8,16,24
    const int rsel = lane & 15;
#pragma unroll
    for (int kk = 0; kk < 64; kk += 32) {
      short8 af[4], bfr[4];
#pragma unroll
      for (int mi = 0; mi < 4; ++mi)
        af[mi] = *(const short8*)&As[(wr * 64 + mi * 16 + rsel) * 72 + kk + kA];
#pragma unroll
      for (int ni = 0; ni < 4; ++ni)
        bfr[ni] = *(const short8*)&Bs[(wc * 64 + ni * 16 + rsel) * 72 + kk + kA];
#pragma unroll
      for (int mi = 0; mi < 4; ++mi)
#pragma unroll
        for (int ni = 0; ni < 4; ++ni)
          acc[mi][ni] = __builtin_amdgcn_mfma_f32_16x16x32_bf16(af[mi], bfr[ni], acc[mi][ni], 0, 0, 0);
    }
    __syncthreads();
  }

  const int crow = (lane >> 4) * 4;
  const int ccol = lane & 15;
  if (OUT_BF) {
#pragma unroll
    for (int mi = 0; mi < 4; ++mi) {
#pragma unroll
      for (int ni = 0; ni < 4; ++ni) {
        int gn = n0 + wc * 64 + ni * 16 + ccol;
        float bv = bias[gn];
#pragma unroll
        for (int i = 0; i < 4; ++i) {
          int gm = m0 + wr * 64 + mi * 16 + crow + i;
          if (gm < M)
            __builtin_nontemporal_store(f2bf(acc[mi][ni][i] + bv),
                                        &((short*)Cptr)[(size_t)gm * N + gn]);
        }
      }
    }
  } else {
#pragma unroll
    for (int p = 0; p < 4; ++p) {
      __syncthreads();
      if (wr == (p >> 1)) {
        int mi0 = (p & 1) * 2;
#pragma unroll
        for (int mm = 0; mm < 2; ++mm) {
#pragma unroll
          for (int ni = 0; ni < 4; ++ni) {
            int c = wc * 64 + ni * 16 + ccol;
#pragma unroll
            for (int i = 0; i < 4; ++i)
              cst[(mm * 16 + crow + i) * 132 + c] = acc[mi0 + mm][ni][i];
          }
        }
      }
      __syncthreads();
#pragma unroll
      for (int rep = 0; rep < 4; ++rep) {
        int cell = tid + rep * 256;        // 0..1023
        int r = cell >> 5, q = cell & 31;  // row 0..31, quad 0..31
        int gm = m0 + p * 32 + r;
        int gn = n0 + q * 4;
        if (gm < M) {
          float4 bv = *(const float4*)&bias[gn];
          floatx4 v;
          v[0] = cst[r * 132 + q * 4 + 0] + bv.x;
          v[1] = cst[r * 132 + q * 4 + 1] + bv.y;
          v[2] = cst[r * 132 + q * 4 + 2] + bv.z;
          v[3] = cst[r * 132 + q * 4 + 3] + bv.w;
          __builtin_nontemporal_store(v, (floatx4*)&((float*)Cptr)[(size_t)gm * N + gn]);
        }
      }
    }
  }
}

// ---------------------------------------------------------------------------
// Fused pre-GEMM: blocks [0,128) = enc_proj split GEMM (M=2048,N=1024,K=2048);
// blocks [128,640) = gates GEMM (M=2016,N=4096,K=512, bf16 out, NT stores).
// ---------------------------------------------------------------------------
__global__ __launch_bounds__(256) void gemm_pre(
    const short* __restrict__ Ah, const short* __restrict__ Al,
    const short* __restrict__ Bt_hi, const short* __restrict__ Bt_lo,
    float* __restrict__ Cenc, const float* __restrict__ battn,
    const short* __restrict__ Ag, const short* __restrict__ Btg,
    short* __restrict__ Cg, const float* __restrict__ brnn_p)
{
  __shared__ char smem[4 * 128 * 72 * 2];   // 73728 B
  const int tid = threadIdx.x;
  const int lane = tid & 63;
  const int wid = tid >> 6;
  const int wr = wid >> 1, wc = wid & 1;
  const int row = tid >> 1;
  const int ks  = (tid & 1) << 5;   // 0 or 32
  const int kA = (lane >> 4) << 3;
  const int rsel = lane & 15;
  const int crow = (lane >> 4) * 4;
  const int ccol = lane & 15;

  if (blockIdx.x < 128) {
    // ---------------- enc_proj split GEMM (K=2048) ----------------
    short* As_hi = (short*)smem;
    short* As_lo = (short*)(smem + 1 * 128 * 72 * 2);
    short* Bs_hi = (short*)(smem + 2 * 128 * 72 * 2);
    short* Bs_lo = (short*)(smem + 3 * 128 * 72 * 2);
    const int K = 2048, N = NH;
    int tile_id = xcd_swz(blockIdx.x, 128);
    const int m0 = (tile_id % 16) * 128;
    const int n0 = (tile_id / 16) * 128;

    floatx4 acc[4][4] = {};
    for (int k0 = 0; k0 < K; k0 += 64) {
      {
        size_t o = (size_t)(m0 + row) * K + k0 + ks;
#pragma unroll
        for (int c = 0; c < 4; ++c) {
          *(short8*)&As_hi[row * 72 + ks + c * 8] = *(const short8*)(Ah + o + c * 8);
          *(short8*)&As_lo[row * 72 + ks + c * 8] = *(const short8*)(Al + o + c * 8);
        }
      }
      {
        size_t o = (size_t)(n0 + row) * K + k0 + ks;
#pragma unroll
        for (int c = 0; c < 4; ++c) {
          *(short8*)&Bs_hi[row * 72 + ks + c * 8] = *(const short8*)(Bt_hi + o + c * 8);
          *(short8*)&Bs_lo[row * 72 + ks + c * 8] = *(const short8*)(Bt_lo + o + c * 8);
        }
      }
      __syncthreads();
#pragma unroll
      for (int kk = 0; kk < 64; kk += 32) {
        short8 ah[4], al[4], bh[4], bl[4];
#pragma unroll
        for (int mi = 0; mi < 4; ++mi) {
          int off = (wr * 64 + mi * 16 + rsel) * 72 + kk + kA;
          ah[mi] = *(const short8*)&As_hi[off];
          al[mi] = *(const short8*)&As_lo[off];
        }
#pragma unroll
        for (int ni = 0; ni < 4; ++ni) {
          int off = (wc * 64 + ni * 16 + rsel) * 72 + kk + kA;
          bh[ni] = *(const short8*)&Bs_hi[off];
          bl[ni] = *(const short8*)&Bs_lo[off];
        }
#pragma unroll
        for (int mi = 0; mi < 4; ++mi)
#pragma unroll
          for (int ni = 0; ni < 4; ++ni) {
            floatx4 a = acc[mi][ni];
            a = __builtin_amdgcn_mfma_f32_16x16x32_bf16(al[mi], bh[ni], a, 0, 0, 0);
            a = __builtin_amdgcn_mfma_f32_16x16x32_bf16(ah[mi], bl[ni], a, 0, 0, 0);
            a = __builtin_amdgcn_mfma_f32_16x16x32_bf16(ah[mi], bh[ni], a, 0, 0, 0);
            acc[mi][ni] = a;
          }
      }
      __syncthreads();
    }
#pragma unroll
    for (int mi = 0; mi < 4; ++mi) {
#pragma unroll
      for (int ni = 0; ni < 4; ++ni) {
        int gn = n0 + wc * 64 + ni * 16 + ccol;
        float bv = battn[gn];
#pragma unroll
        for (int i = 0; i < 4; ++i) {
          int gm = m0 + wr * 64 + mi * 16 + crow + i;
          Cenc[(size_t)gm * N + gn] = acc[mi][ni][i] + bv;
        }
      }
    }
  } else {
    // ---------------- gates GEMM (K=512, bf16 out, NT) ----------------
    short* As = (short*)smem;
    short* Bs = (short*)(smem + 128 * 72 * 2);
    const int K = NE, N = 4096, M = TDEC * NB;
    int tile_id = xcd_swz(blockIdx.x - 128, 512);
    const int m0 = (tile_id % 16) * 128;
    const int n0 = (tile_id / 16) * 128;

    floatx4 acc[4][4] = {};
    for (int k0 = 0; k0 < K; k0 += 64) {
      {
        int gm = m0 + row;
        short8 v0, v1, v2, v3;
        if (gm < M) {
          const short* src = Ag + (size_t)gm * K + k0 + ks;
          v0 = *(const short8*)src;
          v1 = *(const short8*)(src + 8);
          v2 = *(const short8*)(src + 16);
          v3 = *(const short8*)(src + 24);
        } else {
#pragma unroll
          for (int c = 0; c < 8; ++c) { v0[c] = 0; v1[c] = 0; v2[c] = 0; v3[c] = 0; }
        }
        *(short8*)&As[row * 72 + ks]      = v0;
        *(short8*)&As[row * 72 + ks + 8]  = v1;
        *(short8*)&As[row * 72 + ks + 16] = v2;
        *(short8*)&As[row * 72 + ks + 24] = v3;
      }
      {
        const short* src = Btg + (size_t)(n0 + row) * K + k0 + ks;
        *(short8*)&Bs[row * 72 + ks]      = *(const short8*)src;
        *(short8*)&Bs[row * 72 + ks + 8]  = *(const short8*)(src + 8);
        *(short8*)&Bs[row * 72 + ks + 16] = *(const short8*)(src + 16);
        *(short8*)&Bs[row * 72 + ks + 24] = *(const short8*)(src + 24);
      }
      __syncthreads();
#pragma unroll
      for (int kk = 0; kk < 64; kk += 32) {
        short8 af[4], bfr[4];
#pragma unroll
        for (int mi = 0; mi < 4; ++mi)
          af[mi] = *(const short8*)&As[(wr * 64 + mi * 16 + rsel) * 72 + kk + kA];
#pragma unroll
        for (int ni = 0; ni < 4; ++ni)
          bfr[ni] = *(const short8*)&Bs[(wc * 64 + ni * 16 + rsel) * 72 + kk + kA];
#pragma unroll
        for (int mi = 0; mi < 4; ++mi)
#pragma unroll
          for (int ni = 0; ni < 4; ++ni)
            acc[mi][ni] = __builtin_amdgcn_mfma_f32_16x16x32_bf16(af[mi], bfr[ni], acc[mi][ni], 0, 0, 0);
      }
      __syncthreads();
    }
#pragma unroll
    for (int mi = 0; mi < 4; ++mi) {
#pragma unroll
      for (int ni = 0; ni < 4; ++ni) {
        int gn = n0 + wc * 64 + ni * 16 + ccol;
        float bv = brnn_p[gn];
#pragma unroll
        for (int i = 0; i < 4; ++i) {
          int gm = m0 + wr * 64 + mi * 16 + crow + i;
          if (gm < M)
            __builtin_nontemporal_store(f2bf(acc[mi][ni][i] + bv),
                                        &Cg[(size_t)gm * N + gn]);
        }
      }
    }
  }
}

// ---------------------------------------------------------------------------
// LSTM A-step + folded side-work, 701 blocks x 512 threads, t in [0,64):
//   blk [0,128)    : LSTM step t (skips if t >= 63)
//   blk [128,160)  : attention for t-1 (b = blk-128; h(t-1) from prior launch)
//   blk [160,668)  : Wout transpose tiles id = t*508 + (blk-160)  (< 32000)
//   blk [668,701)  : Wcomb split-transpose tiles id = t*33 + (blk-668) (<2048)
// ---------------------------------------------------------------------------
__global__ __launch_bounds__(512) void scan_a(
    int t,
    const short* __restrict__ Whp_hi,  // bf16 [4096 c][1024], c = 4j+gate
    const short* __restrict__ Whp_lo,
    const short* __restrict__ gatesx,  // bf16 [2016 rows t*32+b][4096 c-perm]
    short* __restrict__ hhi_all,       // [65*32][1024] bf16, slot s=t+1
    short* __restrict__ hlo_all,
    float* __restrict__ hf_all,        // [65*32][1024] f32
    float* __restrict__ c_buf,         // [32][1024] f32
    const float* __restrict__ Wout,  short* __restrict__ WoutT,
    const float* __restrict__ Wcomb, short* __restrict__ WcTHi,
    short* __restrict__ WcTLo,
    const float* __restrict__ encp,    // f32 [2048 rows b*64+s][1024]
    short* __restrict__ ctxhi_all,     // [2016 rows t*32+b][1024]
    short* __restrict__ ctxlo_all)
{
  __shared__ float smem[8 * 32 * 33];
  const int blk = blockIdx.x;
  const int tid = threadIdx.x;

  if (blk >= 128 && blk < 160) {
    // ---------------- attention for ta = t-1 ----------------
    const int ta = t - 1;
    if (ta < 0 || ta >= TDEC) return;
    const int b = blk - 128;
    float* h_lds  = smem;            // 1024
    float* part   = smem + 1024;     // 256
    float* sc_lds = smem + 1280;     // 64
    float* p_lds  = smem + 1344;     // 64
    const float* h = hf_all + ((size_t)(ta + 1) * 32 + b) * NH;
    if (tid < 256) ((float4*)h_lds)[tid] = ((const float4*)h)[tid];
    __syncthreads();
    if (tid < 256) {
      int s = tid & 63, kc = tid >> 6;
      const float4* ep = (const float4*)(encp + ((size_t)(b * 64 + s)) * NH + kc * 256);
      const float4* hp = (const float4*)(h_lds + kc * 256);
      float ac0 = 0, ac1 = 0, ac2 = 0, ac3 = 0;
#pragma unroll
      for (int i = 0; i < 64; i += 4) {
        float4 e0 = ep[i],     h0v = hp[i];
        float4 e1 = ep[i + 1], h1v = hp[i + 1];
        float4 e2 = ep[i + 2], h2v = hp[i + 2];
        float4 e3 = ep[i + 3], h3v = hp[i + 3];
        ac0 = fmaf(e0.x, h0v.x, ac0); ac0 = fmaf(e0.y, h0v.y, ac0);
        ac0 = fmaf(e0.z, h0v.z, ac0); ac0 = fmaf(e0.w, h0v.w, ac0);
        ac1 = fmaf(e1.x, h1v.x, ac1); ac1 = fmaf(e1.y, h1v.y, ac1);
        ac1 = fmaf(e1.z, h1v.z, ac1); ac1 = fmaf(e1.w, h1v.w, ac1);
        ac2 = fmaf(e2.x, h2v.x, ac2); ac2 = fmaf(e2.y, h2v.y, ac2);
        ac2 = fmaf(e2.z, h2v.z, ac2); ac2 = fmaf(e2.w, h2v.w, ac2);
        ac3 = fmaf(e3.x, h3v.x, ac3); ac3 = fmaf(e3.y, h3v.y, ac3);
        ac3 = fmaf(e3.z, h3v.z, ac3); ac3 = fmaf(e3.w, h3v.w, ac3);
      }
      part[kc * 64 + s] = (ac0 + ac1) + (ac2 + ac3);
    }
    __syncthreads();
    if (tid < 64) {
      float sc = part[tid] + part[64 + tid] + part[128 + tid] + part[192 + tid];
      sc_lds[tid] = sc;
      float m = sc;
#pragma unroll
      for (int off = 32; off; off >>= 1) m = fmaxf(m, __shfl_xor(m, off));
      float e = expf(sc - m);
      float sum = e;
#pragma unroll
      for (int off = 32; off; off >>= 1) sum += __shfl_xor(sum, off);
      p_lds[tid] = e / sum;
    }
    __syncthreads();
    if (tid < 256) {
      int k4 = tid * 4;
      float a0 = 0, a1 = 0, a2 = 0, a3 = 0;
      const float* ep = encp + (size_t)(b * 64) * NH + k4;
      for (int s = 0; s < 64; ++s) {
        float p = p_lds[s];
        float4 e = *(const float4*)(ep + (size_t)s * NH);
        a0 = fmaf(p, e.x, a0); a1 = fmaf(p, e.y, a1);
        a2 = fmaf(p, e.z, a2); a3 = fmaf(p, e.w, a3);
      }
      size_t crow2 = ((size_t)ta * 32 + b) * NH + k4;
      short4v c4h, c4l;
      float av[4] = {a0, a1, a2, a3};
#pragma unroll
      for (int q = 0; q < 4; ++q) {
        short hh = f2bf(av[q]);
        c4h[q] = hh;
        c4l[q] = f2bf(av[q] - bf2f(hh));
      }
      *(short4v*)(ctxhi_all + crow2) = c4h;
      *(short4v*)(ctxlo_all + crow2) = c4l;
    }
    return;
  }

  if (blk >= 160) {
    float (*tile)[33] = (float(*)[33])smem;
    if (blk < 668) {
      int id = t * 508 + (blk - 160);
      if (id < 32000) {
        int k0 = (id & 31) * 32, n0 = (id >> 5) * 32;
        if (tid < 256) {
          int tx = tid & 31, ty = tid >> 5;
#pragma unroll
          for (int r = 0; r < 32; r += 8)
            tile[ty + r][tx] = Wout[(size_t)(k0 + ty + r) * 32000 + n0 + tx];
        }
        __syncthreads();
        if (tid < 256) {
          int kq = tid & 7, nl = tid >> 3;
          int n = n0 + nl;
          short4v v;
#pragma unroll
          for (int q = 0; q < 4; ++q) v[q] = f2bf(tile[kq * 4 + q][nl]);
          *(short4v*)&WoutT[(size_t)n * 1024 + k0 + kq * 4] = v;
        }
      }
    } else {
      int id = t * 33 + (blk - 668);
      if (id < 2048) {
        int k0 = (id & 63) * 32, n0 = (id >> 6) * 32;
        if (tid < 256) {
          int tx = tid & 31, ty = tid >> 5;
#pragma unroll
          for (int r = 0; r < 32; r += 8)
            tile[ty + r][tx] = Wcomb[(size_t)(k0 + ty + r) * 1024 + n0 + tx];
        }
        __syncthreads();
        if (tid < 256) {
          int kq = tid & 7, nl = tid >> 3;
          int n = n0 + nl;
          short4v vh, vl;
#pragma unroll
          for (int q = 0; q < 4; ++q) {
            float v = tile[kq * 4 + q][nl];
            short h = f2bf(v);
            vh[q] = h;
            vl[q] = f2bf(v - bf2f(h));
          }
          size_t o = (size_t)n * 2048 + k0 + kq * 4;
          *(short4v*)&WcTHi[o] = vh;
          *(short4v*)&WcTLo[o] = vl;
        }
      }
    }
    return;
  }

  // ---------------- LSTM step (blocks 0..127) ----------------
  if (t >= TDEC) return;
  const int lane = tid & 63;
  const int wid = tid >> 6;           // 0..7
  const int rsel = lane & 15;
  const int kA = (lane >> 4) * 8;
  const int crow = (lane >> 4) * 4;
  const int ccol = lane & 15;

  const size_t spv = (size_t)t * (NH * NB);
  const size_t snw = (size_t)(t + 1) * (NH * NB);
  const short* Hh = hhi_all + spv;
  const short* Hl = hlo_all + spv;
  const int c0 = blk * 32;          // this block's 32 perm-cols
  const int kb = wid * 128;         // wave's K-slice

  floatx4 acc[2][2] = {};
  const short* wh0 = Whp_hi + (size_t)(c0 + rsel) * NH + kb + kA;
  const short* wl0 = Whp_lo + (size_t)(c0 + rsel) * NH + kb + kA;
  const short* wh1 = Whp_hi + (size_t)(c0 + 16 + rsel) * NH + kb + kA;
  const short* wl1 = Whp_lo + (size_t)(c0 + 16 + rsel) * NH + kb + kA;
  const short* ha0 = Hh + (size_t)rsel * NH + kb + kA;
  const short* la0 = Hl + (size_t)rsel * NH + kb + kA;
  const short* ha1 = Hh + (size_t)(16 + rsel) * NH + kb + kA;
  const short* la1 = Hl + (size_t)(16 + rsel) * NH + kb + kA;
#pragma unroll
  for (int kk = 0; kk < 4; ++kk) {
    int k0 = kk * 32;
    short8 a0h = *(const short8*)(ha0 + k0);
    short8 a0l = *(const short8*)(la0 + k0);
    short8 a1h = *(const short8*)(ha1 + k0);
    short8 a1l = *(const short8*)(la1 + k0);
    short8 b0h = *(const short8*)(wh0 + k0);
    short8 b0l = *(const short8*)(wl0 + k0);
    short8 b1h = *(const short8*)(wh1 + k0);
    short8 b1l = *(const short8*)(wl1 + k0);
    acc[0][0] = __builtin_amdgcn_mfma_f32_16x16x32_bf16(a0l, b0h, acc[0][0], 0, 0, 0);
    acc[0][0] = __builtin_amdgcn_mfma_f32_16x16x32_bf16(a0h, b0l, acc[0][0], 0, 0, 0);
    acc[0][0] = __builtin_amdgcn_mfma_f32_16x16x32_bf16(a0h, b0h, acc[0][0], 0, 0, 0);
    acc[0][1] = __builtin_amdgcn_mfma_f32_16x16x32_bf16(a0l, b1h, acc[0][1], 0, 0, 0);
    acc[0][1] = __builtin_amdgcn_mfma_f32_16x16x32_bf16(a0h, b1l, acc[0][1], 0, 0, 0);
    acc[0][1] = __builtin_amdgcn_mfma_f32_16x16x32_bf16(a0h, b1h, acc[0][1], 0, 0, 0);
    acc[1][0] = __builtin_amdgcn_mfma_f32_16x16x32_bf16(a1l, b0h, acc[1][0], 0, 0, 0);
    acc[1][0] = __builtin_amdgcn_mfma_f32_16x16x32_bf16(a1h, b0l, acc[1][0], 0, 0, 0);
    acc[1][0] = __builtin_amdgcn_mfma_f32_16x16x32_bf16(a1h, b0h, acc[1][0], 0, 0, 0);
    acc[1][1] = __builtin_amdgcn_mfma_f32_16x16x32_bf16(a1l, b1h, acc[1][1], 0, 0, 0);
    acc[1][1] = __builtin_amdgcn_mfma_f32_16x16x32_bf16(a1h, b1l, acc[1][1], 0, 0, 0);
    acc[1][1] = __builtin_amdgcn_mfma_f32_16x16x32_bf16(a1h, b1h, acc[1][1], 0, 0, 0);
  }
  // partials -> LDS [wave][32 b][33-pad cols]
#pragma unroll
  for (int mi = 0; mi < 2; ++mi)
#pragma unroll
    for (int ni = 0; ni < 2; ++ni)
#pragma unroll
      for (int i = 0; i < 4; ++i)
        smem[wid * 1056 + (mi * 16 + crow + i) * 33 + ni * 16 + ccol] = acc[mi][ni][i];
  __syncthreads();
  if (tid < 256) {
    int b = tid & 31, jl = tid >> 5;     // jl 0..7
    float g[4];
#pragma unroll
    for (int q = 0; q < 4; ++q) {
      float s = 0;
#pragma unroll
      for (int w = 0; w < 8; ++w) s += smem[w * 1056 + b * 33 + jl * 4 + q];
      g[q] = s;
    }
    int jg = (c0 >> 2) + jl;
    const short* gx = gatesx + ((size_t)t * 32 + b) * 4096 + c0 + jl * 4;
    short4v gxv = *(const short4v*)gx;
    float gi = g[0] + bf2f(gxv[0]);
    float gf = g[1] + bf2f(gxv[1]);
    float gg = g[2] + bf2f(gxv[2]);
    float go = g[3] + bf2f(gxv[3]);
    float co = c_buf[b * NH + jg];
    float cn = sigm(gf) * co + sigm(gi) * tanhf(gg);
    float hn = sigm(go) * tanhf(cn);
    c_buf[b * NH + jg] = cn;
    hf_all[snw + b * NH + jg] = hn;
    short hh = f2bf(hn);
    hhi_all[snw + b * NH + jg] = hh;
    hlo_all[snw + b * NH + jg] = f2bf(hn - bf2f(hh));
  }
}

// ---------------------------------------------------------------------------
// Batched comb: outs[b*63+t][n] = tanh([h(t)|ctx(t)] @ WcombT + bcomb), bf16.
// BK=64 (pad-72), XCD-swizzled tiles (grid 16x8 = 128 blocks).
// ---------------------------------------------------------------------------
__global__ __launch_bounds__(256) void gemm_comb(
    const short* __restrict__ Ah_hi,   // hhi_all + 32*NH (row r -> h(t=r/32))
    const short* __restrict__ Ah_lo,
    const short* __restrict__ Cx_hi,   // ctxhi_all (row r)
    const short* __restrict__ Cx_lo,
    const short* __restrict__ Bt_hi,   // WcTHi [1024][2048]
    const short* __restrict__ Bt_lo,
    const float* __restrict__ bcomb,
    short* __restrict__ outs)          // [2016 rows b*63+t][1024]
{
  __shared__ short As_hi[128 * 72];
  __shared__ short As_lo[128 * 72];
  __shared__ short Bs_hi[128 * 72];
  __shared__ short Bs_lo[128 * 72];
  int tile_id = xcd_swz(blockIdx.y * gridDim.x + blockIdx.x, gridDim.x * gridDim.y);
  const int m0 = (tile_id % gridDim.x) * 128;
  const int n0 = (tile_id / gridDim.x) * 128;
  const int tid = threadIdx.x;
  const int lane = tid & 63;
  const int wid = tid >> 6;
  const int wr = wid >> 1, wc = wid & 1;

  floatx4 acc[4][4] = {};
  const int row = tid >> 1;
  const int ks  = (tid & 1) << 5;   // 0 or 32

  for (int k0 = 0; k0 < 2048; k0 += 64) {
    {
      int gr = m0 + row;
      const short* sh;
      const short* sl;
      if (k0 < NH) {     // whole 64-slice within h region (k0 <= 960)
        sh = Ah_hi + (size_t)gr * NH + k0 + ks;
        sl = Ah_lo + (size_t)gr * NH + k0 + ks;
      } else {
        sh = Cx_hi + (size_t)gr * NH + (k0 - NH) + ks;
        sl = Cx_lo + (size_t)gr * NH + (k0 - NH) + ks;
      }
#pragma unroll
      for (int c = 0; c < 4; ++c) {
        *(short8*)&As_hi[row * 72 + ks + c * 8] = *(const short8*)(sh + c * 8);
        *(short8*)&As_lo[row * 72 + ks + c * 8] = *(const short8*)(sl + c * 8);
      }
    }
    {
      size_t o = (size_t)(n0 + row) * 2048 + k0 + ks;
#pragma unroll
      for (int c = 0; c < 4; ++c) {
        *(short8*)&Bs_hi[row * 72 + ks + c * 8] = *(const short8*)(Bt_hi + o + c * 8);
        *(short8*)&Bs_lo[row * 72 + ks + c * 8] = *(const short8*)(Bt_lo + o + c * 8);
      }
    }
    __syncthreads();

    const int kA = (lane >> 4) << 3;
    const int rsel = lane & 15;
#pragma unroll
    for (int kk = 0; kk < 64; kk += 32) {
      short8 ah[4], al[4], bh[4], bl[4];
#pragma unroll
      for (int mi = 0; mi < 4; ++mi) {
        int off = (wr * 64 + mi * 16 + rsel) * 72 + kk + kA;
        ah[mi] = *(const short8*)&As_hi[off];
        al[mi] = *(const short8*)&As_lo[off];
      }
#pragma unroll
      for (int ni = 0; ni < 4; ++ni) {
        int off = (wc * 64 + ni * 16 + rsel) * 72 + kk + kA;
        bh[ni] = *(const short8*)&Bs_hi[off];
        bl[ni] = *(const short8*)&Bs_lo[off];
      }
#pragma unroll
      for (int mi = 0; mi < 4; ++mi)
#pragma unroll
        for (int ni = 0; ni < 4; ++ni) {
          floatx4 a = acc[mi][ni];
          a = __builtin_amdgcn_mfma_f32_16x16x32_bf16(al[mi], bh[ni], a, 0, 0, 0);
          a = __builtin_amdgcn_mfma_f32_16x16x32_bf16(ah[mi], bl[ni], a, 0, 0, 0);
          a = __builtin_amdgcn_mfma_f32_16x16x32_bf16(ah[mi], bh[ni], a, 0, 0, 0);
          acc[mi][ni] = a;
        }
    }
    __syncthreads();
  }

  const int crow = (lane >> 4) * 4;
  const int ccol = lane & 15;
#pragma unroll
  for (int mi = 0; mi < 4; ++mi) {
#pragma unroll
    for (int ni = 0; ni < 4; ++ni) {
      int gn = n0 + wc * 64 + ni * 16 + ccol;
      float bv = bcomb[gn];
#pragma unroll
      for (int i = 0; i < 4; ++i) {
        int gm = m0 + wr * 64 + mi * 16 + crow + i;   // r = t*32+b
        if (gm < TDEC * NB) {
          int tt = gm >> 5, bb = gm & 31;
          outs[((size_t)bb * TDEC + tt) * NH + gn] = f2bf(tanhf(acc[mi][ni][i] + bv));
        }
      }
    }
  }
}

// ---------------------------------------------------------------------------
extern "C" void kernel_launch(void* const* d_in, const int* in_sizes, int n_in,
                              void* d_out, int out_size, void* d_ws, size_t ws_size,
                              hipStream_t stream)
{
  const int*   target = (const int*)  d_in[0];
  const float* src    = (const float*)d_in[1];
  const float* h0     = (const float*)d_in[2];
  const float* c0     = (const float*)d_in[3];
  const float* emb    = (const float*)d_in[4];
  const float* Wih    = (const float*)d_in[5];
  const float* Whh    = (const float*)d_in[6];
  const float* brnn   = (const float*)d_in[7];
  const float* Wattn  = (const float*)d_in[8];
  const float* battn  = (const float*)d_in[9];
  const float* Wcomb  = (const float*)d_in[10];
  const float* bcomb  = (const float*)d_in[11];
  const float* Wout   = (const float*)d_in[12];
  const float* bout   = (const float*)d_in[13];
  float* out = (float*)d_out;

  char* ws = (char*)d_ws;
  size_t off = 0;
  auto take = [&](size_t bytes) { char* p = ws + off; off += (bytes + 255) & ~(size_t)255; return p; };
  short* WoutT    = (short*)take((size_t)NV * NH * 2);            // 64 MB
  short* WattnTh  = (short*)take((size_t)NH * 2048 * 2);          // 4 MB
  short* WattnTl  = (short*)take((size_t)NH * 2048 * 2);          // 4 MB
  short* WihTp    = (short*)take((size_t)4096 * NE * 2);          // 4 MB
  short* WhpHi    = (short*)take((size_t)4096 * NH * 2);          // 8 MB
  short* WhpLo    = (short*)take((size_t)4096 * NH * 2);          // 8 MB
  short* WcTHi    = (short*)take((size_t)NH * 2048 * 2);          // 4 MB
  short* WcTLo    = (short*)take((size_t)NH * 2048 * 2);          // 4 MB
  short* xs_bf    = (short*)take((size_t)TDEC * NB * NE * 2);     // 2 MB
  float* encp     = (float*)take((size_t)NB * NS * NH * 4);       // 8 MB
  short* gatesx   = (short*)take((size_t)TDEC * NB * 4096 * 2);   // 16.5 MB
  short* outs_bf  = (short*)take((size_t)TDEC * NB * NH * 2);     // 4 MB
  float* hf_all   = (float*)take((size_t)65 * NB * NH * 4);       // 8.5 MB
  short* hhi_all  = (short*)take((size_t)65 * NB * NH * 2);       // 4.25 MB
  short* hlo_all  = (short*)take((size_t)65 * NB * NH * 2);       // 4.25 MB
  short* ctxhi_a  = (short*)take((size_t)2048 * NH * 2);          // 4 MB
  short* ctxlo_a  = (short*)take((size_t)2048 * NH * 2);          // 4 MB
  float* c_buf    = (float*)take((size_t)NH * NB * 4);
  float* brnn_p   = (float*)take((size_t)4096 * 4);
  short* sAl      = (short*)take((size_t)2048 * 2048 * 2);        // 8 MB
  short* sAh      = (short*)take((size_t)2048 * 2048 * 2);        // 8 MB (no alias)
  if (off > ws_size) return;

  // 1) prework before the fused pre-GEMM (Wout/Wcomb transposes ride the scan)
  prep_all<<<10240, 256, 0, stream>>>(
      Wattn, Wih, Whh, target, emb, h0, c0, brnn, src,
      WattnTh, WattnTl, WihTp, WhpHi, WhpLo,
      xs_bf, hf_all, hhi_all, hlo_all, c_buf, brnn_p, sAh, sAl);
  // 2) fused enc_proj + gates GEMM (independent outputs, one dispatch)
  gemm_pre<<<640, 256, 0, stream>>>(
      sAh, sAl, WattnTh, WattnTl, encp, battn,
      xs_bf, WihTp, gatesx, brnn_p);
  // 3) LSTM scan: 64 launches; idle blocks run attn(t-1) + Wout/Wcomb transposes
  for (int t = 0; t < TDEC + 1; ++t)
    scan_a<<<701, 512, 0, stream>>>(t, WhpHi, WhpLo, gatesx, hhi_all, hlo_all,
                                    hf_all, c_buf, Wout, WoutT, Wcomb, WcTHi, WcTLo,
                                    encp, ctxhi_a, ctxlo_a);
  // 4) batched comb GEMM -> outs (rows b*63+t), BK=64, XCD-swizzled
  gemm_comb<<<dim3(16, 8), 256, 0, stream>>>(hhi_all + (size_t)32 * NH, hlo_all + (size_t)32 * NH,
                                             ctxhi_a, ctxlo_a, WcTHi, WcTLo, bcomb, outs_bf);
  // 5) logits = outs @ W_out + b_out, XCD-swizzled, BK=64, NT stores
  gemm_kernel<0, 1><<<dim3(16, NV / 128), 256, 0, stream>>>(outs_bf, WoutT, out, bout, TDEC * NB, NV, NH);
}

// Round 24
// 1133.672 us; speedup vs baseline: 1.1922x; 1.1922x over previous
//
#include <hip/hip_runtime.h>
#include <stdint.h>

// Problem constants
#define NB    32      // batch
#define NS    64      // src seq
#define TDEC  63      // decode steps (T-1)
#define NE    512     // embed dim
#define NH    1024    // hidden
#define NV    32000   // vocab

typedef float  floatx4 __attribute__((ext_vector_type(4)));
typedef short  short8  __attribute__((ext_vector_type(8)));
typedef short  short4v __attribute__((ext_vector_type(4)));

__device__ __forceinline__ float bf2f(short s) {
  return __uint_as_float(((uint32_t)(uint16_t)s) << 16);
}
__device__ __forceinline__ short f2bf(float f) {
  uint32_t u = __float_as_uint(f);
  uint32_t r = (u + 0x7fffu + ((u >> 16) & 1u)) >> 16;  // RNE
  return (short)(uint16_t)r;
}
__device__ __forceinline__ float sigm(float x) { return 1.f / (1.f + expf(-x)); }

// XCD-aware bijective block swizzle (valid when nwg % 8 == 0).
__device__ __forceinline__ int xcd_swz(int orig, int nwg) {
  return (orig & 7) * (nwg >> 3) + (orig >> 3);
}

// ---------------------------------------------------------------------------
// Transpose helpers (device): W[K][N] f32 tile(32x32 at bx,by) -> Wt[r(n)][K]
// perm: r = (n&1023)*4 + (n>>10)
// ---------------------------------------------------------------------------
__device__ __forceinline__ void tr_plain(
    const float* __restrict__ W, short* __restrict__ Wt, int K, int N,
    int bx, int by, int perm, float (*tile)[33], int tid)
{
  int k0 = bx * 32, n0 = by * 32;
  int tx = tid & 31, ty = tid >> 5;
#pragma unroll
  for (int r = 0; r < 32; r += 8)
    tile[ty + r][tx] = W[(size_t)(k0 + ty + r) * N + n0 + tx];
  __syncthreads();
  int kq = tid & 7, nl = tid >> 3;
  int n = n0 + nl;
  int rr = perm ? ((n & 1023) * 4 + (n >> 10)) : n;
  short4v v;
#pragma unroll
  for (int q = 0; q < 4; ++q) v[q] = f2bf(tile[kq * 4 + q][nl]);
  *(short4v*)&Wt[(size_t)rr * K + k0 + kq * 4] = v;
}

__device__ __forceinline__ void tr_split(
    const float* __restrict__ W, short* __restrict__ Wt_hi, short* __restrict__ Wt_lo,
    int K, int N, int bx, int by, int perm, float (*tile)[33], int tid)
{
  int k0 = bx * 32, n0 = by * 32;
  int tx = tid & 31, ty = tid >> 5;
#pragma unroll
  for (int r = 0; r < 32; r += 8)
    tile[ty + r][tx] = W[(size_t)(k0 + ty + r) * N + n0 + tx];
  __syncthreads();
  int kq = tid & 7, nl = tid >> 3;
  int n = n0 + nl;
  int rr = perm ? ((n & 1023) * 4 + (n >> 10)) : n;
  short4v vh, vl;
#pragma unroll
  for (int q = 0; q < 4; ++q) {
    float v = tile[kq * 4 + q][nl];
    short h = f2bf(v);
    vh[q] = h;
    vl[q] = f2bf(v - bf2f(h));
  }
  size_t o = (size_t)rr * K + k0 + kq * 4;
  *(short4v*)&Wt_hi[o] = vh;
  *(short4v*)&Wt_lo[o] = vl;
}

// ---------------------------------------------------------------------------
// prep_all: prework needed BEFORE the fused pre-GEMM: Wattn split, Wih perm,
// Whh split perm, gathers + src hi/lo split. 10240 blocks.
// ---------------------------------------------------------------------------
__global__ __launch_bounds__(256) void prep_all(
    const float* __restrict__ Wattn, const float* __restrict__ Wih,
    const float* __restrict__ Whh,
    const int* __restrict__ target,  const float* __restrict__ emb,
    const float* __restrict__ h0,    const float* __restrict__ c0,
    const float* __restrict__ brnn,  const float* __restrict__ src,
    short* __restrict__ WattnTh, short* __restrict__ WattnTl,
    short* __restrict__ WihTp,
    short* __restrict__ WhpHi,   short* __restrict__ WhpLo,
    short* __restrict__ xs, float* __restrict__ hf_all,
    short* __restrict__ hhi_all, short* __restrict__ hlo_all,
    float* __restrict__ c_buf, float* __restrict__ brnn_p,
    short* __restrict__ sAh, short* __restrict__ sAl)
{
  __shared__ float tile[32][33];
  const int blk = blockIdx.x;
  const int tid = threadIdx.x;

  if (blk < 2048) {
    tr_split(Wattn, WattnTh, WattnTl, 2048, 1024, blk & 63, blk >> 6, 0, tile, tid);
  } else if (blk < 4096) {
    int b = blk - 2048;
    tr_plain(Wih, WihTp, 512, 4096, b & 15, b >> 4, 1, tile, tid);
  } else if (blk < 8192) {
    int b = blk - 4096;
    tr_split(Whh, WhpHi, WhpLo, 1024, 4096, b & 31, b >> 5, 1, tile, tid);
  } else {
    const int NXS = TDEC * NB * NE;            // 1032192
    const int HN = NH * NB;                    // 32768
    const int NSRC = 2048 * 2048;              // 4194304
    int total = NXS + 2 * HN + 4096 + NSRC;
    int b = blk - 8192;                        // 0..2047
    for (int idx = b * 256 + tid; idx < total; idx += 2048 * 256) {
      if (idx < NXS) {
        int row = idx >> 9, e = idx & 511;     // row = t*32+b
        int t = row >> 5, bb = row & 31;
        int token = target[bb * 64 + t];
        xs[idx] = f2bf(emb[(size_t)token * NE + e]);
      } else if (idx < NXS + HN) {
        int r = idx - NXS;
        float v = h0[r];                       // [b][k], slot 0
        hf_all[r] = v;
        short hh = f2bf(v);
        hhi_all[r] = hh;
        hlo_all[r] = f2bf(v - bf2f(hh));
      } else if (idx < NXS + 2 * HN) {
        int r = idx - NXS - HN;
        c_buf[r] = c0[r];
      } else if (idx < NXS + 2 * HN + 4096) {
        int c = idx - NXS - 2 * HN;
        brnn_p[c] = brnn[(c & 3) * 1024 + (c >> 2)];
      } else {
        int e = idx - NXS - 2 * HN - 4096;
        float v = src[e];
        short h = f2bf(v);
        sAh[e] = h;
        sAl[e] = f2bf(v - bf2f(h));
      }
    }
  }
}

// ---------------------------------------------------------------------------
// bf16 MFMA GEMM: C[M][N] = A[M][K] * Bt[N][K]^T + bias.
// BK=64 K-loop (32 MFMA per barrier pair, pad-72 LDS, K % 64 == 0).
// SWZ=1: XCD-aware tile swizzle. f32-out epilogue cst overlays As/Bs.
// Output stores NONTEMPORAL (write-once streams).
// ---------------------------------------------------------------------------
template<int OUT_BF, int SWZ>
__global__ __launch_bounds__(256) void gemm_kernel(
    const short* __restrict__ Ab, const short* __restrict__ Bt,
    void* __restrict__ Cptr, const float* __restrict__ bias,
    int M, int N, int K)
{
  __shared__ char smem[2 * 128 * 72 * 2];   // 36864B: As | Bs; epilogue cst overlay
  short* As = (short*)smem;                 // [128*72]
  short* Bs = (short*)(smem + 128 * 72 * 2);
  float* cst = (float*)smem;                // f32-out epilogue staging (16896B)
  int tile_id = blockIdx.y * gridDim.x + blockIdx.x;
  if (SWZ) tile_id = xcd_swz(tile_id, gridDim.x * gridDim.y);
  const int m0 = (tile_id % gridDim.x) * 128;
  const int n0 = (tile_id / gridDim.x) * 128;
  const int tid = threadIdx.x;
  const int lane = tid & 63;
  const int wid = tid >> 6;
  const int wr = wid >> 1, wc = wid & 1;

  floatx4 acc[4][4] = {};
  const int row = tid >> 1;          // 0..127
  const int ks  = (tid & 1) << 5;    // 0 or 32

  for (int k0 = 0; k0 < K; k0 += 64) {
    {
      int gm = m0 + row;
      short8 v0, v1, v2, v3;
      if (gm < M) {
        const short* src = Ab + (size_t)gm * K + k0 + ks;
        v0 = *(const short8*)src;
        v1 = *(const short8*)(src + 8);
        v2 = *(const short8*)(src + 16);
        v3 = *(const short8*)(src + 24);
      } else {
#pragma unroll
        for (int c = 0; c < 8; ++c) { v0[c] = 0; v1[c] = 0; v2[c] = 0; v3[c] = 0; }
      }
      *(short8*)&As[row * 72 + ks]      = v0;
      *(short8*)&As[row * 72 + ks + 8]  = v1;
      *(short8*)&As[row * 72 + ks + 16] = v2;
      *(short8*)&As[row * 72 + ks + 24] = v3;
    }
    {
      const short* src = Bt + (size_t)(n0 + row) * K + k0 + ks;
      *(short8*)&Bs[row * 72 + ks]      = *(const short8*)src;
      *(short8*)&Bs[row * 72 + ks + 8]  = *(const short8*)(src + 8);
      *(short8*)&Bs[row * 72 + ks + 16] = *(const short8*)(src + 16);
      *(short8*)&Bs[row * 72 + ks + 24] = *(const short8*)(src + 24);
    }
    __syncthreads();

    const int kA = (lane >> 4) << 3;   // 0,8,16,24
    const int rsel = lane & 15;
#pragma unroll
    for (int kk = 0; kk < 64; kk += 32) {
      short8 af[4], bfr[4];
#pragma unroll
      for (int mi = 0; mi < 4; ++mi)
        af[mi] = *(const short8*)&As[(wr * 64 + mi * 16 + rsel) * 72 + kk + kA];
#pragma unroll
      for (int ni = 0; ni < 4; ++ni)
        bfr[ni] = *(const short8*)&Bs[(wc * 64 + ni * 16 + rsel) * 72 + kk + kA];
#pragma unroll
      for (int mi = 0; mi < 4; ++mi)
#pragma unroll
        for (int ni = 0; ni < 4; ++ni)
          acc[mi][ni] = __builtin_amdgcn_mfma_f32_16x16x32_bf16(af[mi], bfr[ni], acc[mi][ni], 0, 0, 0);
    }
    __syncthreads();
  }

  const int crow = (lane >> 4) * 4;
  const int ccol = lane & 15;
  if (OUT_BF) {
#pragma unroll
    for (int mi = 0; mi < 4; ++mi) {
#pragma unroll
      for (int ni = 0; ni < 4; ++ni) {
        int gn = n0 + wc * 64 + ni * 16 + ccol;
        float bv = bias[gn];
#pragma unroll
        for (int i = 0; i < 4; ++i) {
          int gm = m0 + wr * 64 + mi * 16 + crow + i;
          if (gm < M)
            __builtin_nontemporal_store(f2bf(acc[mi][ni][i] + bv),
                                        &((short*)Cptr)[(size_t)gm * N + gn]);
        }
      }
    }
  } else {
#pragma unroll
    for (int p = 0; p < 4; ++p) {
      __syncthreads();
      if (wr == (p >> 1)) {
        int mi0 = (p & 1) * 2;
#pragma unroll
        for (int mm = 0; mm < 2; ++mm) {
#pragma unroll
          for (int ni = 0; ni < 4; ++ni) {
            int c = wc * 64 + ni * 16 + ccol;
#pragma unroll
            for (int i = 0; i < 4; ++i)
              cst[(mm * 16 + crow + i) * 132 + c] = acc[mi0 + mm][ni][i];
          }
        }
      }
      __syncthreads();
#pragma unroll
      for (int rep = 0; rep < 4; ++rep) {
        int cell = tid + rep * 256;        // 0..1023
        int r = cell >> 5, q = cell & 31;  // row 0..31, quad 0..31
        int gm = m0 + p * 32 + r;
        int gn = n0 + q * 4;
        if (gm < M) {
          float4 bv = *(const float4*)&bias[gn];
          floatx4 v;
          v[0] = cst[r * 132 + q * 4 + 0] + bv.x;
          v[1] = cst[r * 132 + q * 4 + 1] + bv.y;
          v[2] = cst[r * 132 + q * 4 + 2] + bv.z;
          v[3] = cst[r * 132 + q * 4 + 3] + bv.w;
          __builtin_nontemporal_store(v, (floatx4*)&((float*)Cptr)[(size_t)gm * N + gn]);
        }
      }
    }
  }
}

// ---------------------------------------------------------------------------
// Fused pre-GEMM: blocks [0,128) = enc_proj split GEMM (M=2048,N=1024,K=2048);
// blocks [128,640) = gates GEMM (M=2016,N=4096,K=512, bf16 out, NT stores).
// Independent outputs (sAh no longer aliases gatesx) -> safe concurrency.
// Shared static LDS = 73728 B (enc path size; gates path uses a subset).
// ---------------------------------------------------------------------------
__global__ __launch_bounds__(256) void gemm_pre(
    const short* __restrict__ Ah, const short* __restrict__ Al,
    const short* __restrict__ Bt_hi, const short* __restrict__ Bt_lo,
    float* __restrict__ Cenc, const float* __restrict__ battn,
    const short* __restrict__ Ag, const short* __restrict__ Btg,
    short* __restrict__ Cg, const float* __restrict__ brnn_p)
{
  __shared__ char smem[4 * 128 * 72 * 2];   // 73728 B
  const int tid = threadIdx.x;
  const int lane = tid & 63;
  const int wid = tid >> 6;
  const int wr = wid >> 1, wc = wid & 1;
  const int row = tid >> 1;
  const int ks  = (tid & 1) << 5;   // 0 or 32
  const int kA = (lane >> 4) << 3;
  const int rsel = lane & 15;
  const int crow = (lane >> 4) * 4;
  const int ccol = lane & 15;

  if (blockIdx.x < 128) {
    // ---------------- enc_proj split GEMM (K=2048) ----------------
    short* As_hi = (short*)smem;
    short* As_lo = (short*)(smem + 1 * 128 * 72 * 2);
    short* Bs_hi = (short*)(smem + 2 * 128 * 72 * 2);
    short* Bs_lo = (short*)(smem + 3 * 128 * 72 * 2);
    const int K = 2048, N = NH;
    int tile_id = xcd_swz(blockIdx.x, 128);
    const int m0 = (tile_id % 16) * 128;
    const int n0 = (tile_id / 16) * 128;

    floatx4 acc[4][4] = {};
    for (int k0 = 0; k0 < K; k0 += 64) {
      {
        size_t o = (size_t)(m0 + row) * K + k0 + ks;
#pragma unroll
        for (int c = 0; c < 4; ++c) {
          *(short8*)&As_hi[row * 72 + ks + c * 8] = *(const short8*)(Ah + o + c * 8);
          *(short8*)&As_lo[row * 72 + ks + c * 8] = *(const short8*)(Al + o + c * 8);
        }
      }
      {
        size_t o = (size_t)(n0 + row) * K + k0 + ks;
#pragma unroll
        for (int c = 0; c < 4; ++c) {
          *(short8*)&Bs_hi[row * 72 + ks + c * 8] = *(const short8*)(Bt_hi + o + c * 8);
          *(short8*)&Bs_lo[row * 72 + ks + c * 8] = *(const short8*)(Bt_lo + o + c * 8);
        }
      }
      __syncthreads();
#pragma unroll
      for (int kk = 0; kk < 64; kk += 32) {
        short8 ah[4], al[4], bh[4], bl[4];
#pragma unroll
        for (int mi = 0; mi < 4; ++mi) {
          int off = (wr * 64 + mi * 16 + rsel) * 72 + kk + kA;
          ah[mi] = *(const short8*)&As_hi[off];
          al[mi] = *(const short8*)&As_lo[off];
        }
#pragma unroll
        for (int ni = 0; ni < 4; ++ni) {
          int off = (wc * 64 + ni * 16 + rsel) * 72 + kk + kA;
          bh[ni] = *(const short8*)&Bs_hi[off];
          bl[ni] = *(const short8*)&Bs_lo[off];
        }
#pragma unroll
        for (int mi = 0; mi < 4; ++mi)
#pragma unroll
          for (int ni = 0; ni < 4; ++ni) {
            floatx4 a = acc[mi][ni];
            a = __builtin_amdgcn_mfma_f32_16x16x32_bf16(al[mi], bh[ni], a, 0, 0, 0);
            a = __builtin_amdgcn_mfma_f32_16x16x32_bf16(ah[mi], bl[ni], a, 0, 0, 0);
            a = __builtin_amdgcn_mfma_f32_16x16x32_bf16(ah[mi], bh[ni], a, 0, 0, 0);
            acc[mi][ni] = a;
          }
      }
      __syncthreads();
    }
#pragma unroll
    for (int mi = 0; mi < 4; ++mi) {
#pragma unroll
      for (int ni = 0; ni < 4; ++ni) {
        int gn = n0 + wc * 64 + ni * 16 + ccol;
        float bv = battn[gn];
#pragma unroll
        for (int i = 0; i < 4; ++i) {
          int gm = m0 + wr * 64 + mi * 16 + crow + i;
          Cenc[(size_t)gm * N + gn] = acc[mi][ni][i] + bv;
        }
      }
    }
  } else {
    // ---------------- gates GEMM (K=512, bf16 out, NT) ----------------
    short* As = (short*)smem;
    short* Bs = (short*)(smem + 128 * 72 * 2);
    const int K = NE, N = 4096, M = TDEC * NB;
    int tile_id = xcd_swz(blockIdx.x - 128, 512);
    const int m0 = (tile_id % 16) * 128;
    const int n0 = (tile_id / 16) * 128;

    floatx4 acc[4][4] = {};
    for (int k0 = 0; k0 < K; k0 += 64) {
      {
        int gm = m0 + row;
        short8 v0, v1, v2, v3;
        if (gm < M) {
          const short* src = Ag + (size_t)gm * K + k0 + ks;
          v0 = *(const short8*)src;
          v1 = *(const short8*)(src + 8);
          v2 = *(const short8*)(src + 16);
          v3 = *(const short8*)(src + 24);
        } else {
#pragma unroll
          for (int c = 0; c < 8; ++c) { v0[c] = 0; v1[c] = 0; v2[c] = 0; v3[c] = 0; }
        }
        *(short8*)&As[row * 72 + ks]      = v0;
        *(short8*)&As[row * 72 + ks + 8]  = v1;
        *(short8*)&As[row * 72 + ks + 16] = v2;
        *(short8*)&As[row * 72 + ks + 24] = v3;
      }
      {
        const short* src = Btg + (size_t)(n0 + row) * K + k0 + ks;
        *(short8*)&Bs[row * 72 + ks]      = *(const short8*)src;
        *(short8*)&Bs[row * 72 + ks + 8]  = *(const short8*)(src + 8);
        *(short8*)&Bs[row * 72 + ks + 16] = *(const short8*)(src + 16);
        *(short8*)&Bs[row * 72 + ks + 24] = *(const short8*)(src + 24);
      }
      __syncthreads();
#pragma unroll
      for (int kk = 0; kk < 64; kk += 32) {
        short8 af[4], bfr[4];
#pragma unroll
        for (int mi = 0; mi < 4; ++mi)
          af[mi] = *(const short8*)&As[(wr * 64 + mi * 16 + rsel) * 72 + kk + kA];
#pragma unroll
        for (int ni = 0; ni < 4; ++ni)
          bfr[ni] = *(const short8*)&Bs[(wc * 64 + ni * 16 + rsel) * 72 + kk + kA];
#pragma unroll
        for (int mi = 0; mi < 4; ++mi)
#pragma unroll
          for (int ni = 0; ni < 4; ++ni)
            acc[mi][ni] = __builtin_amdgcn_mfma_f32_16x16x32_bf16(af[mi], bfr[ni], acc[mi][ni], 0, 0, 0);
      }
      __syncthreads();
    }
#pragma unroll
    for (int mi = 0; mi < 4; ++mi) {
#pragma unroll
      for (int ni = 0; ni < 4; ++ni) {
        int gn = n0 + wc * 64 + ni * 16 + ccol;
        float bv = brnn_p[gn];
#pragma unroll
        for (int i = 0; i < 4; ++i) {
          int gm = m0 + wr * 64 + mi * 16 + crow + i;
          if (gm < M)
            __builtin_nontemporal_store(f2bf(acc[mi][ni][i] + bv),
                                        &Cg[(size_t)gm * N + gn]);
        }
      }
    }
  }
}

// ---------------------------------------------------------------------------
// LSTM A-step + folded weight-transpose side-work, 669 blocks x 512 threads:
//   blk [0,128)    : LSTM step t
//   blk [128,636)  : Wout transpose tiles id = t*508 + (blk-128)  (< 32000)
//   blk [636,669)  : Wcomb split-transpose tiles id = t*33 + (blk-636) (< 2048)
// ---------------------------------------------------------------------------
__global__ __launch_bounds__(512) void scan_a(
    int t,
    const short* __restrict__ Whp_hi,  // bf16 [4096 c][1024], c = 4j+gate
    const short* __restrict__ Whp_lo,
    const short* __restrict__ gatesx,  // bf16 [2016 rows t*32+b][4096 c-perm]
    short* __restrict__ hhi_all,       // [65*32][1024] bf16, slot s=t+1
    short* __restrict__ hlo_all,
    float* __restrict__ hf_all,        // [65*32][1024] f32
    float* __restrict__ c_buf,         // [32][1024] f32
    const float* __restrict__ Wout,  short* __restrict__ WoutT,
    const float* __restrict__ Wcomb, short* __restrict__ WcTHi,
    short* __restrict__ WcTLo)
{
  __shared__ float smem[8 * 32 * 33];
  const int blk = blockIdx.x;
  const int tid = threadIdx.x;

  if (blk >= 128) {
    float (*tile)[33] = (float(*)[33])smem;
    if (blk < 636) {
      int id = t * 508 + (blk - 128);
      if (id < 32000) {
        int k0 = (id & 31) * 32, n0 = (id >> 5) * 32;
        if (tid < 256) {
          int tx = tid & 31, ty = tid >> 5;
#pragma unroll
          for (int r = 0; r < 32; r += 8)
            tile[ty + r][tx] = Wout[(size_t)(k0 + ty + r) * 32000 + n0 + tx];
        }
        __syncthreads();
        if (tid < 256) {
          int kq = tid & 7, nl = tid >> 3;
          int n = n0 + nl;
          short4v v;
#pragma unroll
          for (int q = 0; q < 4; ++q) v[q] = f2bf(tile[kq * 4 + q][nl]);
          *(short4v*)&WoutT[(size_t)n * 1024 + k0 + kq * 4] = v;
        }
      }
    } else {
      int id = t * 33 + (blk - 636);
      if (id < 2048) {
        int k0 = (id & 63) * 32, n0 = (id >> 6) * 32;
        if (tid < 256) {
          int tx = tid & 31, ty = tid >> 5;
#pragma unroll
          for (int r = 0; r < 32; r += 8)
            tile[ty + r][tx] = Wcomb[(size_t)(k0 + ty + r) * 1024 + n0 + tx];
        }
        __syncthreads();
        if (tid < 256) {
          int kq = tid & 7, nl = tid >> 3;
          int n = n0 + nl;
          short4v vh, vl;
#pragma unroll
          for (int q = 0; q < 4; ++q) {
            float v = tile[kq * 4 + q][nl];
            short h = f2bf(v);
            vh[q] = h;
            vl[q] = f2bf(v - bf2f(h));
          }
          size_t o = (size_t)n * 2048 + k0 + kq * 4;
          *(short4v*)&WcTHi[o] = vh;
          *(short4v*)&WcTLo[o] = vl;
        }
      }
    }
    return;
  }

  // ---------------- LSTM step (blocks 0..127) ----------------
  const int lane = tid & 63;
  const int wid = tid >> 6;           // 0..7
  const int rsel = lane & 15;
  const int kA = (lane >> 4) * 8;
  const int crow = (lane >> 4) * 4;
  const int ccol = lane & 15;

  const size_t spv = (size_t)t * (NH * NB);
  const size_t snw = (size_t)(t + 1) * (NH * NB);
  const short* Hh = hhi_all + spv;
  const short* Hl = hlo_all + spv;
  const int c0 = blk * 32;          // this block's 32 perm-cols
  const int kb = wid * 128;         // wave's K-slice

  floatx4 acc[2][2] = {};
  const short* wh0 = Whp_hi + (size_t)(c0 + rsel) * NH + kb + kA;
  const short* wl0 = Whp_lo + (size_t)(c0 + rsel) * NH + kb + kA;
  const short* wh1 = Whp_hi + (size_t)(c0 + 16 + rsel) * NH + kb + kA;
  const short* wl1 = Whp_lo + (size_t)(c0 + 16 + rsel) * NH + kb + kA;
  const short* ha0 = Hh + (size_t)rsel * NH + kb + kA;
  const short* la0 = Hl + (size_t)rsel * NH + kb + kA;
  const short* ha1 = Hh + (size_t)(16 + rsel) * NH + kb + kA;
  const short* la1 = Hl + (size_t)(16 + rsel) * NH + kb + kA;
#pragma unroll
  for (int kk = 0; kk < 4; ++kk) {
    int k0 = kk * 32;
    short8 a0h = *(const short8*)(ha0 + k0);
    short8 a0l = *(const short8*)(la0 + k0);
    short8 a1h = *(const short8*)(ha1 + k0);
    short8 a1l = *(const short8*)(la1 + k0);
    short8 b0h = *(const short8*)(wh0 + k0);
    short8 b0l = *(const short8*)(wl0 + k0);
    short8 b1h = *(const short8*)(wh1 + k0);
    short8 b1l = *(const short8*)(wl1 + k0);
    acc[0][0] = __builtin_amdgcn_mfma_f32_16x16x32_bf16(a0l, b0h, acc[0][0], 0, 0, 0);
    acc[0][0] = __builtin_amdgcn_mfma_f32_16x16x32_bf16(a0h, b0l, acc[0][0], 0, 0, 0);
    acc[0][0] = __builtin_amdgcn_mfma_f32_16x16x32_bf16(a0h, b0h, acc[0][0], 0, 0, 0);
    acc[0][1] = __builtin_amdgcn_mfma_f32_16x16x32_bf16(a0l, b1h, acc[0][1], 0, 0, 0);
    acc[0][1] = __builtin_amdgcn_mfma_f32_16x16x32_bf16(a0h, b1l, acc[0][1], 0, 0, 0);
    acc[0][1] = __builtin_amdgcn_mfma_f32_16x16x32_bf16(a0h, b1h, acc[0][1], 0, 0, 0);
    acc[1][0] = __builtin_amdgcn_mfma_f32_16x16x32_bf16(a1l, b0h, acc[1][0], 0, 0, 0);
    acc[1][0] = __builtin_amdgcn_mfma_f32_16x16x32_bf16(a1h, b0l, acc[1][0], 0, 0, 0);
    acc[1][0] = __builtin_amdgcn_mfma_f32_16x16x32_bf16(a1h, b0h, acc[1][0], 0, 0, 0);
    acc[1][1] = __builtin_amdgcn_mfma_f32_16x16x32_bf16(a1l, b1h, acc[1][1], 0, 0, 0);
    acc[1][1] = __builtin_amdgcn_mfma_f32_16x16x32_bf16(a1h, b1l, acc[1][1], 0, 0, 0);
    acc[1][1] = __builtin_amdgcn_mfma_f32_16x16x32_bf16(a1h, b1h, acc[1][1], 0, 0, 0);
  }
  // partials -> LDS [wave][32 b][33-pad cols]
#pragma unroll
  for (int mi = 0; mi < 2; ++mi)
#pragma unroll
    for (int ni = 0; ni < 2; ++ni)
#pragma unroll
      for (int i = 0; i < 4; ++i)
        smem[wid * 1056 + (mi * 16 + crow + i) * 33 + ni * 16 + ccol] = acc[mi][ni][i];
  __syncthreads();
  if (tid < 256) {
    int b = tid & 31, jl = tid >> 5;     // jl 0..7
    float g[4];
#pragma unroll
    for (int q = 0; q < 4; ++q) {
      float s = 0;
#pragma unroll
      for (int w = 0; w < 8; ++w) s += smem[w * 1056 + b * 33 + jl * 4 + q];
      g[q] = s;
    }
    int jg = (c0 >> 2) + jl;
    const short* gx = gatesx + ((size_t)t * 32 + b) * 4096 + c0 + jl * 4;
    short4v gxv = *(const short4v*)gx;
    float gi = g[0] + bf2f(gxv[0]);
    float gf = g[1] + bf2f(gxv[1]);
    float gg = g[2] + bf2f(gxv[2]);
    float go = g[3] + bf2f(gxv[3]);
    float co = c_buf[b * NH + jg];
    float cn = sigm(gf) * co + sigm(gi) * tanhf(gg);
    float hn = sigm(go) * tanhf(cn);
    c_buf[b * NH + jg] = cn;
    hf_all[snw + b * NH + jg] = hn;
    short hh = f2bf(hn);
    hhi_all[snw + b * NH + jg] = hh;
    hlo_all[snw + b * NH + jg] = f2bf(hn - bf2f(hh));
  }
}

// ---------------------------------------------------------------------------
// Batched attention: 2016 blocks x 256 threads, logical block = b*63 + t.
// XCD-swizzled: per-XCD encp working set 1MB (L2-fits).
// ---------------------------------------------------------------------------
__global__ __launch_bounds__(256) void attn_batch(
    const float* __restrict__ encp,    // f32 [2048 rows b*64+s][1024]
    const float* __restrict__ hf_all,  // [65*32][1024], slot t+1
    short* __restrict__ ctxhi_all,     // [2016 rows t*32+b][1024]
    short* __restrict__ ctxlo_all)
{
  __shared__ float h_lds[NH];
  __shared__ float part[4 * 64];
  __shared__ float sc_lds[64];
  __shared__ float p_lds[64];
  const int blk = xcd_swz(blockIdx.x, gridDim.x);
  const int b = blk / TDEC;
  const int t = blk % TDEC;
  const int tid = threadIdx.x;
  const float* h = hf_all + ((size_t)(t + 1) * 32 + b) * NH;

  ((float4*)h_lds)[tid] = ((const float4*)h)[tid];
  __syncthreads();
  {
    int s = tid & 63, kc = tid >> 6;
    const float4* ep = (const float4*)(encp + ((size_t)(b * 64 + s)) * NH + kc * 256);
    const float4* hp = (const float4*)(h_lds + kc * 256);
    float ac0 = 0, ac1 = 0, ac2 = 0, ac3 = 0;
#pragma unroll
    for (int i = 0; i < 64; i += 4) {
      float4 e0 = ep[i],     h0v = hp[i];
      float4 e1 = ep[i + 1], h1v = hp[i + 1];
      float4 e2 = ep[i + 2], h2v = hp[i + 2];
      float4 e3 = ep[i + 3], h3v = hp[i + 3];
      ac0 = fmaf(e0.x, h0v.x, ac0); ac0 = fmaf(e0.y, h0v.y, ac0);
      ac0 = fmaf(e0.z, h0v.z, ac0); ac0 = fmaf(e0.w, h0v.w, ac0);
      ac1 = fmaf(e1.x, h1v.x, ac1); ac1 = fmaf(e1.y, h1v.y, ac1);
      ac1 = fmaf(e1.z, h1v.z, ac1); ac1 = fmaf(e1.w, h1v.w, ac1);
      ac2 = fmaf(e2.x, h2v.x, ac2); ac2 = fmaf(e2.y, h2v.y, ac2);
      ac2 = fmaf(e2.z, h2v.z, ac2); ac2 = fmaf(e2.w, h2v.w, ac2);
      ac3 = fmaf(e3.x, h3v.x, ac3); ac3 = fmaf(e3.y, h3v.y, ac3);
      ac3 = fmaf(e3.z, h3v.z, ac3); ac3 = fmaf(e3.w, h3v.w, ac3);
    }
    part[kc * 64 + s] = (ac0 + ac1) + (ac2 + ac3);
  }
  __syncthreads();
  if (tid < 64) {
    float sc = part[tid] + part[64 + tid] + part[128 + tid] + part[192 + tid];
    sc_lds[tid] = sc;
    float m = sc;
#pragma unroll
    for (int off = 32; off; off >>= 1) m = fmaxf(m, __shfl_xor(m, off));
    float e = expf(sc - m);
    float sum = e;
#pragma unroll
    for (int off = 32; off; off >>= 1) sum += __shfl_xor(sum, off);
    p_lds[tid] = e / sum;
  }
  __syncthreads();
  {
    int k4 = tid * 4;
    float a0 = 0, a1 = 0, a2 = 0, a3 = 0;
    const float* ep = encp + (size_t)(b * 64) * NH + k4;
    for (int s = 0; s < 64; ++s) {
      float p = p_lds[s];
      float4 e = *(const float4*)(ep + (size_t)s * NH);
      a0 = fmaf(p, e.x, a0); a1 = fmaf(p, e.y, a1);
      a2 = fmaf(p, e.z, a2); a3 = fmaf(p, e.w, a3);
    }
    size_t crow = ((size_t)t * 32 + b) * NH + k4;
    short4v c4h, c4l;
    float av[4] = {a0, a1, a2, a3};
#pragma unroll
    for (int q = 0; q < 4; ++q) {
      short hh = f2bf(av[q]);
      c4h[q] = hh;
      c4l[q] = f2bf(av[q] - bf2f(hh));
    }
    *(short4v*)(ctxhi_all + crow) = c4h;
    *(short4v*)(ctxlo_all + crow) = c4l;
  }
}

// ---------------------------------------------------------------------------
// Batched comb: outs[b*63+t][n] = tanh([h(t)|ctx(t)] @ WcombT + bcomb), bf16.
// BK=64 (pad-72), XCD-swizzled tiles (grid 16x8 = 128 blocks).
// ---------------------------------------------------------------------------
__global__ __launch_bounds__(256) void gemm_comb(
    const short* __restrict__ Ah_hi,   // hhi_all + 32*NH (row r -> h(t=r/32))
    const short* __restrict__ Ah_lo,
    const short* __restrict__ Cx_hi,   // ctxhi_all (row r)
    const short* __restrict__ Cx_lo,
    const short* __restrict__ Bt_hi,   // WcTHi [1024][2048]
    const short* __restrict__ Bt_lo,
    const float* __restrict__ bcomb,
    short* __restrict__ outs)          // [2016 rows b*63+t][1024]
{
  __shared__ short As_hi[128 * 72];
  __shared__ short As_lo[128 * 72];
  __shared__ short Bs_hi[128 * 72];
  __shared__ short Bs_lo[128 * 72];
  int tile_id = xcd_swz(blockIdx.y * gridDim.x + blockIdx.x, gridDim.x * gridDim.y);
  const int m0 = (tile_id % gridDim.x) * 128;
  const int n0 = (tile_id / gridDim.x) * 128;
  const int tid = threadIdx.x;
  const int lane = tid & 63;
  const int wid = tid >> 6;
  const int wr = wid >> 1, wc = wid & 1;

  floatx4 acc[4][4] = {};
  const int row = tid >> 1;
  const int ks  = (tid & 1) << 5;   // 0 or 32

  for (int k0 = 0; k0 < 2048; k0 += 64) {
    {
      int gr = m0 + row;
      const short* sh;
      const short* sl;
      if (k0 < NH) {     // whole 64-slice within h region (k0 <= 960)
        sh = Ah_hi + (size_t)gr * NH + k0 + ks;
        sl = Ah_lo + (size_t)gr * NH + k0 + ks;
      } else {
        sh = Cx_hi + (size_t)gr * NH + (k0 - NH) + ks;
        sl = Cx_lo + (size_t)gr * NH + (k0 - NH) + ks;
      }
#pragma unroll
      for (int c = 0; c < 4; ++c) {
        *(short8*)&As_hi[row * 72 + ks + c * 8] = *(const short8*)(sh + c * 8);
        *(short8*)&As_lo[row * 72 + ks + c * 8] = *(const short8*)(sl + c * 8);
      }
    }
    {
      size_t o = (size_t)(n0 + row) * 2048 + k0 + ks;
#pragma unroll
      for (int c = 0; c < 4; ++c) {
        *(short8*)&Bs_hi[row * 72 + ks + c * 8] = *(const short8*)(Bt_hi + o + c * 8);
        *(short8*)&Bs_lo[row * 72 + ks + c * 8] = *(const short8*)(Bt_lo + o + c * 8);
      }
    }
    __syncthreads();

    const int kA = (lane >> 4) << 3;
    const int rsel = lane & 15;
#pragma unroll
    for (int kk = 0; kk < 64; kk += 32) {
      short8 ah[4], al[4], bh[4], bl[4];
#pragma unroll
      for (int mi = 0; mi < 4; ++mi) {
        int off = (wr * 64 + mi * 16 + rsel) * 72 + kk + kA;
        ah[mi] = *(const short8*)&As_hi[off];
        al[mi] = *(const short8*)&As_lo[off];
      }
#pragma unroll
      for (int ni = 0; ni < 4; ++ni) {
        int off = (wc * 64 + ni * 16 + rsel) * 72 + kk + kA;
        bh[ni] = *(const short8*)&Bs_hi[off];
        bl[ni] = *(const short8*)&Bs_lo[off];
      }
#pragma unroll
      for (int mi = 0; mi < 4; ++mi)
#pragma unroll
        for (int ni = 0; ni < 4; ++ni) {
          floatx4 a = acc[mi][ni];
          a = __builtin_amdgcn_mfma_f32_16x16x32_bf16(al[mi], bh[ni], a, 0, 0, 0);
          a = __builtin_amdgcn_mfma_f32_16x16x32_bf16(ah[mi], bl[ni], a, 0, 0, 0);
          a = __builtin_amdgcn_mfma_f32_16x16x32_bf16(ah[mi], bh[ni], a, 0, 0, 0);
          acc[mi][ni] = a;
        }
    }
    __syncthreads();
  }

  const int crow = (lane >> 4) * 4;
  const int ccol = lane & 15;
#pragma unroll
  for (int mi = 0; mi < 4; ++mi) {
#pragma unroll
    for (int ni = 0; ni < 4; ++ni) {
      int gn = n0 + wc * 64 + ni * 16 + ccol;
      float bv = bcomb[gn];
#pragma unroll
      for (int i = 0; i < 4; ++i) {
        int gm = m0 + wr * 64 + mi * 16 + crow + i;   // r = t*32+b
        if (gm < TDEC * NB) {
          int tt = gm >> 5, bb = gm & 31;
          outs[((size_t)bb * TDEC + tt) * NH + gn] = f2bf(tanhf(acc[mi][ni][i] + bv));
        }
      }
    }
  }
}

// ---------------------------------------------------------------------------
extern "C" void kernel_launch(void* const* d_in, const int* in_sizes, int n_in,
                              void* d_out, int out_size, void* d_ws, size_t ws_size,
                              hipStream_t stream)
{
  const int*   target = (const int*)  d_in[0];
  const float* src    = (const float*)d_in[1];
  const float* h0     = (const float*)d_in[2];
  const float* c0     = (const float*)d_in[3];
  const float* emb    = (const float*)d_in[4];
  const float* Wih    = (const float*)d_in[5];
  const float* Whh    = (const float*)d_in[6];
  const float* brnn   = (const float*)d_in[7];
  const float* Wattn  = (const float*)d_in[8];
  const float* battn  = (const float*)d_in[9];
  const float* Wcomb  = (const float*)d_in[10];
  const float* bcomb  = (const float*)d_in[11];
  const float* Wout   = (const float*)d_in[12];
  const float* bout   = (const float*)d_in[13];
  float* out = (float*)d_out;

  char* ws = (char*)d_ws;
  size_t off = 0;
  auto take = [&](size_t bytes) { char* p = ws + off; off += (bytes + 255) & ~(size_t)255; return p; };
  short* WoutT    = (short*)take((size_t)NV * NH * 2);            // 64 MB
  short* WattnTh  = (short*)take((size_t)NH * 2048 * 2);          // 4 MB
  short* WattnTl  = (short*)take((size_t)NH * 2048 * 2);          // 4 MB
  short* WihTp    = (short*)take((size_t)4096 * NE * 2);          // 4 MB
  short* WhpHi    = (short*)take((size_t)4096 * NH * 2);          // 8 MB
  short* WhpLo    = (short*)take((size_t)4096 * NH * 2);          // 8 MB
  short* WcTHi    = (short*)take((size_t)NH * 2048 * 2);          // 4 MB
  short* WcTLo    = (short*)take((size_t)NH * 2048 * 2);          // 4 MB
  short* xs_bf    = (short*)take((size_t)TDEC * NB * NE * 2);     // 2 MB
  float* encp     = (float*)take((size_t)NB * NS * NH * 4);       // 8 MB
  short* gatesx   = (short*)take((size_t)TDEC * NB * 4096 * 2);   // 16.5 MB
  short* outs_bf  = (short*)take((size_t)TDEC * NB * NH * 2);     // 4 MB
  float* hf_all   = (float*)take((size_t)65 * NB * NH * 4);       // 8.5 MB
  short* hhi_all  = (short*)take((size_t)65 * NB * NH * 2);       // 4.25 MB
  short* hlo_all  = (short*)take((size_t)65 * NB * NH * 2);       // 4.25 MB
  short* ctxhi_a  = (short*)take((size_t)2048 * NH * 2);          // 4 MB
  short* ctxlo_a  = (short*)take((size_t)2048 * NH * 2);          // 4 MB
  float* c_buf    = (float*)take((size_t)NH * NB * 4);
  float* brnn_p   = (float*)take((size_t)4096 * 4);
  short* sAl      = (short*)take((size_t)2048 * 2048 * 2);        // 8 MB
  short* sAh      = (short*)take((size_t)2048 * 2048 * 2);        // 8 MB (no alias)
  if (off > ws_size) return;

  // 1) prework before the fused pre-GEMM (Wout/Wcomb transposes ride the scan)
  prep_all<<<10240, 256, 0, stream>>>(
      Wattn, Wih, Whh, target, emb, h0, c0, brnn, src,
      WattnTh, WattnTl, WihTp, WhpHi, WhpLo,
      xs_bf, hf_all, hhi_all, hlo_all, c_buf, brnn_p, sAh, sAl);
  // 2) fused enc_proj + gates GEMM (independent outputs, one dispatch)
  gemm_pre<<<640, 256, 0, stream>>>(
      sAh, sAl, WattnTh, WattnTl, encp, battn,
      xs_bf, WihTp, gatesx, brnn_p);
  // 3) sequential LSTM scan: 63 launches; idle blocks do Wout/Wcomb transposes
  for (int t = 0; t < TDEC; ++t)
    scan_a<<<669, 512, 0, stream>>>(t, WhpHi, WhpLo, gatesx, hhi_all, hlo_all,
                                    hf_all, c_buf, Wout, WoutT, Wcomb, WcTHi, WcTLo);
  // 4) batched attention for all (b,t), XCD-swizzled for encp L2 locality
  attn_batch<<<TDEC * NB, 256, 0, stream>>>(encp, hf_all, ctxhi_a, ctxlo_a);
  // 5) batched comb GEMM -> outs (rows b*63+t), BK=64, XCD-swizzled
  gemm_comb<<<dim3(16, 8), 256, 0, stream>>>(hhi_all + (size_t)32 * NH, hlo_all + (size_t)32 * NH,
                                             ctxhi_a, ctxlo_a, WcTHi, WcTLo, bcomb, outs_bf);
  // 6) logits = outs @ W_out + b_out, XCD-swizzled, BK=64, NT stores
  gemm_kernel<0, 1><<<dim3(16, NV / 128), 256, 0, stream>>>(outs_bf, WoutT, out, bout, TDEC * NB, NV, NH);
}